// Round 3
// baseline (352.905 us; speedup 1.0000x reference)
//
#include <hip/hip_runtime.h>
#include <math.h>

#define Bn 32
#define An 8732
#define Cn 201
#define Gn 50

#define RPB 16                                // rows (anchors) per block in cls kernel
#define NTILES ((An + RPB - 1) / RPB)         // 546 tiles per batch (last tile = 12 rows)

// ---------- helpers ----------
__device__ __forceinline__ unsigned int f2key(float f) {
    unsigned int u = __float_as_uint(f);
    return (u & 0x80000000u) ? ~u : (u | 0x80000000u);
}
__device__ __forceinline__ float key2f(unsigned int k) {
    return (k & 0x80000000u) ? __uint_as_float(k & 0x7FFFFFFFu) : __uint_as_float(~k);
}
__device__ __forceinline__ float smooth_l1(float d) {
    float ad = fabsf(d);
    return ad < 1.0f ? 0.5f * d * d : ad - 0.5f;
}

// ---------- kernel 0: zero per-batch accumulators (ws re-poisoned each call) ----------
__global__ void init_kernel(int* fg_count, float* fg_cls_sum, float* bbox_sum) {
    int i = threadIdx.x;
    if (i < Bn) { fg_count[i] = 0; fg_cls_sum[i] = 0.f; bbox_sum[i] = 0.f; }
}

// ---------- kernel 1: per-anchor CE. LDS-staged tile (float4 coalesced), 16 lanes/row ----------
__global__ __launch_bounds__(256) void cls_kernel(
        const float* __restrict__ cls_logits,      // [B,A,C]
        const int*   __restrict__ matched_idxs,    // [B,A]
        const int*   __restrict__ labels,          // [B,G]
        const float* __restrict__ boxes,           // [B,G,4]
        const float* __restrict__ anchors,         // [B,A,4]
        const float* __restrict__ bbox_regression, // [B,A,4]
        float* __restrict__ neg_loss,              // [B,A] out
        int*   __restrict__ fg_count,              // [B]
        float* __restrict__ fg_cls_sum,            // [B]
        float* __restrict__ bbox_sum) {            // [B]
    __shared__ float tile[RPB * Cn];               // 12864 B, 16B-aligned
    int b     = blockIdx.y;
    int tile0 = blockIdx.x * RPB;                  // first anchor of this tile
    int rows  = An - tile0; if (rows > RPB) rows = RPB;   // 16 or 12: rows*Cn % 4 == 0
    int nvec  = rows * Cn / 4;

    // stage: tile base byte offset = (b*An + tile0)*Cn*4; RPB*Cn*4 = 12864 ≡ 0 (mod 16)
    const float4* g  = (const float4*)(cls_logits + ((size_t)b * An + tile0) * Cn);
    float4*       t4 = (float4*)tile;
    for (int i = threadIdx.x; i < nvec; i += 256) t4[i] = g[i];
    __syncthreads();

    int r   = threadIdx.x >> 4;   // row within tile, 0..15 (4 rows per wave)
    int sub = threadIdx.x & 15;   // lane within row group
    if (r >= rows) return;
    const float* row = tile + r * Cn;

    // 201 elements over 16 lanes: sub + 16j, j=0..12 (j=12 only for sub<9)
    float v[13];
    #pragma unroll
    for (int j = 0; j < 12; ++j) v[j] = row[sub + 16 * j];
    bool has12 = (sub < Cn - 192);
    v[12] = has12 ? row[sub + 192] : -INFINITY;

    float mx = v[0];
    #pragma unroll
    for (int j = 1; j < 13; ++j) mx = fmaxf(mx, v[j]);
    #pragma unroll
    for (int off = 8; off; off >>= 1) mx = fmaxf(mx, __shfl_xor(mx, off, 64));

    float s = 0.f;
    #pragma unroll
    for (int j = 0; j < 12; ++j) s += expf(v[j] - mx);
    if (has12) s += expf(v[12] - mx);
    #pragma unroll
    for (int off = 8; off; off >>= 1) s += __shfl_xor(s, off, 64);

    if (sub == 0) {
        size_t row_idx = (size_t)b * An + tile0 + r;
        float lse = mx + logf(s);
        int   mi  = matched_idxs[row_idx];
        bool  fg  = (mi >= 0);
        int   t   = fg ? labels[b * Gn + mi] : 0;
        float cl  = lse - row[t];
        if (fg) {
            neg_loss[row_idx] = -INFINITY;
            atomicAdd(&fg_cls_sum[b], cl);
            atomicAdd(&fg_count[b], 1);
            const float* gt = boxes           + (size_t)(b * Gn + mi) * 4;
            const float* an = anchors         + row_idx * 4;
            const float* rg = bbox_regression + row_idx * 4;
            float aw  = an[2] - an[0], ah  = an[3] - an[1];
            float acx = an[0] + 0.5f * aw, acy = an[1] + 0.5f * ah;
            float gw  = gt[2] - gt[0], gh  = gt[3] - gt[1];
            float gcx = gt[0] + 0.5f * gw, gcy = gt[1] + 0.5f * gh;
            float t0 = 10.f * (gcx - acx) / aw;
            float t1 = 10.f * (gcy - acy) / ah;
            float t2 = 5.f * logf(gw / aw);
            float t3 = 5.f * logf(gh / ah);
            float sum = smooth_l1(rg[0] - t0) + smooth_l1(rg[1] - t1)
                      + smooth_l1(rg[2] - t2) + smooth_l1(rg[3] - t3);
            atomicAdd(&bbox_sum[b], sum);
        } else {
            neg_loss[row_idx] = cl;
        }
    }
}

// ---------- kernel 2: per-batch top-k sum via register-resident bit binary search ----------
#define MIT 9   // ceil(8732 / 1024) elements per thread
__global__ __launch_bounds__(1024) void mining_kernel(
        const float* __restrict__ neg_loss,   // [B,A]
        const int*   __restrict__ fg_count,   // [B]
        float* __restrict__ topk_batch) {     // [B] out
    int b    = blockIdx.x;
    int tid  = threadIdx.x;
    int lane = tid & 63;
    __shared__ int   cnts[32];
    __shared__ float sh_sum;
    __shared__ int   sh_cnt;

    int fc = fg_count[b];
    int k  = 3 * fc;
    int nneg = An - fc;
    if (k > nneg) k = nneg;
    if (k <= 0) {
        if (tid == 0) topk_batch[b] = 0.f;
        return;
    }

    // pads and fg(-inf) keys are < f2key(0.0)=0x80000000 <= any real CE loss,
    // and k <= #negatives guarantees the k-th largest is a real loss.
    const float* vals = neg_loss + (size_t)b * An;
    unsigned int key[MIT];
    #pragma unroll
    for (int j = 0; j < MIT; ++j) {
        int i = tid + j * 1024;
        key[j] = (i < An) ? f2key(vals[i]) : 0u;
    }

    if (tid < 32) cnts[tid] = 0;
    if (tid == 0) { sh_sum = 0.f; sh_cnt = 0; }
    __syncthreads();

    // T = max{t : count(key >= t) >= k}  ==  k-th largest key (MSB-first greedy)
    unsigned int T = 0u;
    for (int bit = 31; bit >= 0; --bit) {
        unsigned int cand = T | (1u << bit);
        int c = 0;
        #pragma unroll
        for (int j = 0; j < MIT; ++j) c += (key[j] >= cand);
        #pragma unroll
        for (int off = 32; off; off >>= 1) c += __shfl_xor(c, off, 64);
        if (lane == 0) atomicAdd(&cnts[bit], c);
        __syncthreads();
        if (cnts[bit] >= k) T = cand;
    }

    // exact sum: strictly-greater elements + tie correction at the threshold
    float fs = 0.f; int cgt = 0;
    #pragma unroll
    for (int j = 0; j < MIT; ++j)
        if (key[j] > T) { fs += key2f(key[j]); cgt++; }
    #pragma unroll
    for (int off = 32; off; off >>= 1) {
        fs  += __shfl_xor(fs,  off, 64);
        cgt += __shfl_xor(cgt, off, 64);
    }
    if (lane == 0) { atomicAdd(&sh_sum, fs); atomicAdd(&sh_cnt, cgt); }
    __syncthreads();
    if (tid == 0)
        topk_batch[b] = sh_sum + (float)(k - sh_cnt) * key2f(T);
}

// ---------- kernel 3: finalize (one wave) ----------
__global__ void finalize_kernel(
        const int*   __restrict__ fg_count,
        const float* __restrict__ fg_cls_sum,
        const float* __restrict__ bbox_sum,
        const float* __restrict__ topk_batch,
        const float* __restrict__ rejection_logits,  // [B,2]
        const int*   __restrict__ image_label,       // [B]
        float* __restrict__ out) {
    int lane = threadIdx.x;
    int   fc = (lane < Bn) ? fg_count[lane]   : 0;
    float tk = (lane < Bn) ? topk_batch[lane] : 0.f;
    float cs = (lane < Bn) ? fg_cls_sum[lane] : 0.f;
    float bs = (lane < Bn) ? bbox_sum[lane]   : 0.f;
    float vl = 0.f;
    if (lane < Bn) {
        float r0 = rejection_logits[lane * 2];
        float r1 = rejection_logits[lane * 2 + 1];
        float m  = fmaxf(r0, r1);
        float lse = m + logf(expf(r0 - m) + expf(r1 - m));
        vl = lse - ((image_label[lane] == 0) ? r0 : r1);
    }
    #pragma unroll
    for (int off = 32; off; off >>= 1) {
        fc += __shfl_xor(fc, off, 64);
        tk += __shfl_xor(tk, off, 64);
        cs += __shfl_xor(cs, off, 64);
        bs += __shfl_xor(bs, off, 64);
        vl += __shfl_xor(vl, off, 64);
    }
    if (lane == 0) {
        float N   = (float)((fc > 1) ? fc : 1);
        float reg = bs / N;
        float cls = (cs + tk) / N;   // N_neg = 0 (MIN_NEG_SAMPLES = 0)
        float val = vl / (float)Bn;
        float loss = 0.5f * (reg + cls) + 0.5f * val;
        out[0] = loss; out[1] = reg; out[2] = cls; out[3] = val;
    }
}

extern "C" void kernel_launch(void* const* d_in, const int* in_sizes, int n_in,
                              void* d_out, int out_size, void* d_ws, size_t ws_size,
                              hipStream_t stream) {
    const float* boxes            = (const float*)d_in[0];
    const int*   labels           = (const int*)  d_in[1];
    const int*   image_label      = (const int*)  d_in[2];
    const float* bbox_regression  = (const float*)d_in[3];
    const float* cls_logits       = (const float*)d_in[4];
    const float* rejection_logits = (const float*)d_in[5];
    const float* anchors          = (const float*)d_in[6];
    const int*   matched_idxs     = (const int*)  d_in[7];
    float* out = (float*)d_out;

    // workspace layout
    float* neg_loss   = (float*)d_ws;                 // B*A floats
    int*   fg_count   = (int*)(neg_loss + Bn * An);   // B
    float* fg_cls_sum = (float*)(fg_count + Bn);      // B
    float* bbox_sum   = fg_cls_sum + Bn;              // B
    float* topk_batch = bbox_sum + Bn;                // B

    init_kernel<<<1, 64, 0, stream>>>(fg_count, fg_cls_sum, bbox_sum);

    dim3 grid(NTILES, Bn);
    cls_kernel<<<grid, 256, 0, stream>>>(cls_logits, matched_idxs, labels,
                                         boxes, anchors, bbox_regression,
                                         neg_loss, fg_count, fg_cls_sum, bbox_sum);

    mining_kernel<<<Bn, 1024, 0, stream>>>(neg_loss, fg_count, topk_batch);

    finalize_kernel<<<1, 64, 0, stream>>>(fg_count, fg_cls_sum, bbox_sum, topk_batch,
                                          rejection_logits, image_label, out);
}